// Round 1
// baseline (721.437 us; speedup 1.0000x reference)
//
#include <hip/hip_runtime.h>

// LSTM anomaly detector: B=4096, T=512, I=3, H=64 (4H=256 gates)
// R4: latency-hiding via 2 independent blocks/CU.
//  - ROWS=8 batch rows per block, grid=512 -> 2 blocks/CU, 2 waves/SIMD.
//    Independent barriers: one block's barrier/ds_read stall is covered by
//    the other block's MFMA/VALU work.
//  - x-contribution moved OFF the MFMA pipe: exact fp32 VALU FMAs
//    (48 fma/lane/step) seeding the MFMA C operand. Cuts 36->24 MFMA/wave,
//    which pays for the half-garbage M=16 tiles. x pre-packed per 64-step
//    chunk into LDS [t][row][4] fp32 -> 4 broadcast ds_read_b128/step.
//    xpart load+compute hoisted BEFORE the barrier (hides under convergence).
//  - decoder rotates across waves (w == t&3) -> no systematic wave-0 skew.
// Garbage rows 8..15: lanes q>=2 read duplicated real x rows -> state stays
// bounded; MFMA row m depends only on A row m, so garbage never leaks.

#define TLEN 512
#define TCHUNK 64
#define ROWS 8

typedef float  float4_t __attribute__((ext_vector_type(4)));
typedef __bf16 bf16x8   __attribute__((ext_vector_type(8)));

__device__ __forceinline__ float fexp2(float x){ return __builtin_amdgcn_exp2f(x); }
__device__ __forceinline__ float frcp (float x){ return __builtin_amdgcn_rcpf(x); }
__device__ __forceinline__ float sigm (float x){ return frcp(1.f + fexp2(-1.44269504f*x)); }
__device__ __forceinline__ float tanh_(float x){ return 1.f - 2.f*frcp(1.f + fexp2(2.88539008f*x)); }

// setup-only RNE split (weights; cost irrelevant)
__device__ __forceinline__ void split8(const float* v, bf16x8& hi, bf16x8& lo){
  #pragma unroll
  for (int j = 0; j < 8; j++){
    __bf16 h = (__bf16)v[j];
    hi[j] = h;
    lo[j] = (__bf16)(v[j] - (float)h);
  }
}

#define MFMA(a,b,c) __builtin_amdgcn_mfma_f32_16x16x32_bf16((a),(b),(c),0,0,0)

// ---- LDS layout ----
// ushort region (bf16): h exchange, double-buffered
#define HHI 0                 // 2 x [16 rows][72] (stride 72 -> 16B-aligned rows)
#define HLO 2304
#define HS_SZ 4608
// float region:
#define XOF 0                 // [8 rows][196] fp32 raw x staging
#define XPK (8*196)           // [64 t][8 rows][4] packed {x0,x1,x2,0}
#define OOF (XPK + 64*8*4)    // [8 rows][196] fp32 out staging
#define LF_SZ (OOF + 8*196)

__global__ __launch_bounds__(256, 2)
void LSTMAnomalyDetector_kernel(
    const float* __restrict__ x,     const float* __restrict__ W_ih,
    const float* __restrict__ W_hh,  const float* __restrict__ b_ih,
    const float* __restrict__ b_hh,  const float* __restrict__ W_dec,
    const float* __restrict__ b_dec, float* __restrict__ out)
{
  __shared__ __align__(16) unsigned short HS[HS_SZ];
  __shared__ __align__(16) float          LF[LF_SZ];

  const int tid  = threadIdx.x;
  const int w    = tid >> 6;        // wave 0..3
  const int lane = tid & 63;
  const int q    = lane >> 4;       // quad 0..3
  const int lid  = lane & 15;
  const int b0   = blockIdx.x * ROWS; // batch rows [b0, b0+ROWS)
  const int cw   = w*16 + lid;      // this lane's H-column

  // ---- resident weight fragments (B-operand: B[k=kt*32+q*8+j][n=lid]) ----
  bf16x8 Bh[4][2], Bl[4][2];  // W_hh^T hi/lo; tl = gate type (i,f,g,o)
  bf16x8 Dh[2],    Dl[2];     // decoder: W_dec^T (cols 0..2 valid)
  float  wi[4][3], bsum[4];   // fp32 x-path: W_ih row + (b_ih+b_hh)

  #pragma unroll
  for (int tl = 0; tl < 4; tl++){
    const int g = tl*64 + cw;                   // gate row (W_hh[256][64] row-major)
    #pragma unroll
    for (int kt = 0; kt < 2; kt++){
      const float* p = W_hh + g*64 + kt*32 + q*8;
      float v[8];
      #pragma unroll
      for (int j = 0; j < 8; j++) v[j] = p[j];
      split8(v, Bh[tl][kt], Bl[tl][kt]);
    }
    wi[tl][0] = W_ih[g*3+0];
    wi[tl][1] = W_ih[g*3+1];
    wi[tl][2] = W_ih[g*3+2];
    bsum[tl]  = b_ih[g] + b_hh[g];
  }
  #pragma unroll
  for (int kt = 0; kt < 2; kt++){
    float v[8] = {0.f,0.f,0.f,0.f,0.f,0.f,0.f,0.f};
    if (lid < 3){
      const float* p = W_dec + lid*64 + kt*32 + q*8;
      #pragma unroll
      for (int j = 0; j < 8; j++) v[j] = p[j];
    }
    split8(v, Dh[kt], Dl[kt]);
  }
  const float bdec = (lid < 3) ? b_dec[lid] : 0.f;

  // ---- state ----
  bf16x8 ah[2] = {}, al[2] = {};             // A-frags of h_{t-1} (hi/lo); h_{-1}=0
  float creg[4] = {0.f, 0.f, 0.f, 0.f};      // c for (row q*4+r, col cw)
  float4_t xp4[4];                           // fp32 x-part, one float4 (rows) per gate

  // xpart loader: 4 broadcast ds_read_b128 + 48 fma. Lanes q>=2 (garbage rows)
  // read duplicated real rows -> bounded state, no NaN.
  auto loadx = [&](int d){
    const int xb = XPK + d*32 + (q & 1)*16;
    #pragma unroll
    for (int r = 0; r < 4; r++){
      float4_t xv = *(const float4_t*)&LF[xb + r*4];
      #pragma unroll
      for (int tl = 0; tl < 4; tl++)
        xp4[tl][r] = fmaf(wi[tl][2], xv[2],
                      fmaf(wi[tl][1], xv[1],
                        fmaf(wi[tl][0], xv[0], bsum[tl])));
    }
  };

  // ---- preload + pack x chunk 0 ----
  #pragma unroll
  for (int s = 0; s < 2; s++){
    const int f = tid + 256*s;
    if (f < 384){
      const int row = f/48; const int off = (f%48)*4;
      float4_t v = *(const float4_t*)(x + (size_t)(b0+row)*1536 + off);
      *(float4_t*)&LF[XOF + row*196 + off] = v;
    }
  }
  __syncthreads();
  #pragma unroll
  for (int s = 0; s < 2; s++){
    const int p = tid + 256*s;                 // p = t*8 + row
    const float* xr = &LF[XOF + (p & 7)*196 + (p >> 3)*3];
    float4_t v = {xr[0], xr[1], xr[2], 0.f};
    *(float4_t*)&LF[XPK + p*4] = v;
  }
  __syncthreads();
  loadx(0);

  for (int t = 0; t < TLEN; ++t){
    const int dt = t & (TCHUNK-1);
    const int hb = (t & 1) * 1152;

    // gate preacts: accB seeded with exact fp32 x-part; 6 MFMAs/tile
    float4_t g4[4];
    #pragma unroll
    for (int tl = 0; tl < 4; tl++){
      float4_t accA = {0.f,0.f,0.f,0.f};
      accA = MFMA(ah[0], Bh[tl][0], accA);
      accA = MFMA(ah[1], Bh[tl][1], accA);
      accA = MFMA(al[0], Bh[tl][0], accA);
      accA = MFMA(al[1], Bh[tl][1], accA);
      float4_t accB = xp4[tl];
      accB = MFMA(ah[0], Bl[tl][0], accB);
      accB = MFMA(ah[1], Bl[tl][1], accB);
      g4[tl] = accA + accB;
    }

    // lane-local activations + c/h update; PRODUCER-SIDE trunc-split of h
    #pragma unroll
    for (int r = 0; r < 4; r++){
      const float ig = sigm (g4[0][r]);
      const float fg = sigm (g4[1][r]);
      const float gg = tanh_(g4[2][r]);
      const float og = sigm (g4[3][r]);
      creg[r] = fg*creg[r] + ig*gg;
      const float h = og * tanh_(creg[r]);
      const unsigned u  = __float_as_uint(h);
      const float    lf = h - __uint_as_float(u & 0xFFFF0000u);   // exact
      const int m = q*4 + r;
      HS[HHI + hb + m*72 + cw] = (unsigned short)(u >> 16);
      HS[HLO + hb + m*72 + cw] = (unsigned short)(__float_as_uint(lf) >> 16);
    }

    // prefetch next step's x-part BEFORE the barrier (hides under convergence)
    if (dt != TCHUNK-1) loadx(dt+1);

    __syncthreads();   // the ONE barrier per step

    // rebuild h A-frags: 4 raw ds_read_b128, zero VALU
    {
      const unsigned short* ph = &HS[HHI + hb + lid*72 + q*8];
      const unsigned short* pl = &HS[HLO + hb + lid*72 + q*8];
      ah[0] = *(const bf16x8*)&ph[0];
      ah[1] = *(const bf16x8*)&ph[32];
      al[0] = *(const bf16x8*)&pl[0];
      al[1] = *(const bf16x8*)&pl[32];
    }

    // decoder rotates across waves: out_t = h_t @ W_dec^T + b_dec -> OOF
    if (w == (t & 3)){
      float4_t d = {0.f,0.f,0.f,0.f};
      d = MFMA(ah[0], Dh[0], d);
      d = MFMA(ah[1], Dh[1], d);
      d = MFMA(al[0], Dh[0], d);
      d = MFMA(al[1], Dh[1], d);
      d = MFMA(ah[0], Dl[0], d);
      d = MFMA(ah[1], Dl[1], d);
      if (lid < 3 && q < 2){
        #pragma unroll
        for (int r = 0; r < 4; r++)
          LF[OOF + (q*4+r)*196 + dt*3 + lid] = d[r] + bdec;
      }
    }

    // chunk boundary: flush out, stage+pack next x chunk
    if (dt == TCHUNK-1){
      __syncthreads();
      const int t0 = t - (TCHUNK-1);
      #pragma unroll
      for (int s = 0; s < 2; s++){
        const int f = tid + 256*s;
        if (f < 384){
          const int row = f/48; const int off = (f%48)*4;
          float4_t v = *(const float4_t*)&LF[OOF + row*196 + off];
          *(float4_t*)(out + (size_t)(b0+row)*1536 + t0*3 + off) = v;
        }
      }
      if (t + 1 < TLEN){
        #pragma unroll
        for (int s = 0; s < 2; s++){
          const int f = tid + 256*s;
          if (f < 384){
            const int row = f/48; const int off = (f%48)*4;
            float4_t v = *(const float4_t*)(x + (size_t)(b0+row)*1536 + (t+1)*3 + off);
            *(float4_t*)&LF[XOF + row*196 + off] = v;
          }
        }
        __syncthreads();
        #pragma unroll
        for (int s = 0; s < 2; s++){
          const int p = tid + 256*s;
          const float* xr = &LF[XOF + (p & 7)*196 + (p >> 3)*3];
          float4_t v = {xr[0], xr[1], xr[2], 0.f};
          *(float4_t*)&LF[XPK + p*4] = v;
        }
      }
      __syncthreads();
      if (t + 1 < TLEN) loadx(0);
    }
  }
}

extern "C" void kernel_launch(void* const* d_in, const int* in_sizes, int n_in,
                              void* d_out, int out_size, void* d_ws, size_t ws_size,
                              hipStream_t stream)
{
  const float* x     = (const float*)d_in[0];
  const float* W_ih  = (const float*)d_in[1];
  const float* W_hh  = (const float*)d_in[2];
  const float* b_ih  = (const float*)d_in[3];
  const float* b_hh  = (const float*)d_in[4];
  const float* W_dec = (const float*)d_in[5];
  const float* b_dec = (const float*)d_in[6];
  float* out = (float*)d_out;

  const int B = in_sizes[0] / (TLEN * 3);   // 4096
  const int blocks = B / ROWS;              // 512
  hipLaunchKernelGGL(LSTMAnomalyDetector_kernel, dim3(blocks), dim3(256), 0, stream,
                     x, W_ih, W_hh, b_ih, b_hh, W_dec, b_dec, out);
}

// Round 4
// 538.850 us; speedup vs baseline: 1.3388x; 1.3388x over previous
//
#include <hip/hip_runtime.h>

// LSTM anomaly detector: B=4096, T=512, I=3, H=64 (4H=256 gates)
// R7: gate-tile split across 8 waves -> 2 waves/SIMD at CONSTANT total work,
// using ONLY the R3/R4-harness-verified math (no packed rows, no shfl pairing).
//  - ROWS=16, grid=256, 512 threads (8 waves), 1 block/CU, 2 waves/SIMD.
//  - Wave (wg = w&3, half = w>>2): computes gates {i,f} (half=0) or {g,o}
//    (half=1) for H-cols [wg*16, wg*16+16). 12 MFMAs/wave/step (2 tiles x 6:
//    hi*Bh, lo*Bh, hi*Bl over full k -- bit-identical terms to R4's pass).
//  - Halves exchange COMPLETE gate preacts via LDS with pure lane-indexed
//    slots (no fragment-layout assumptions): half=0 sends i,f regs 2,3 and
//    receives g,o regs 0,1; activates rows q*4+{0,1}. half=1 symmetric.
//    20 transcendentals/lane (vs R3's 40), zero duplication.
//  - x-path exact fp32 VALU (24 fma/lane), prefetched; trunc h-split (R4's).
//  - 2 barriers/step (exchange, h-ready). Decoder rotates over 8 waves.

#define TLEN 512
#define TCHUNK 64
#define ROWS 16

typedef float  float4_t __attribute__((ext_vector_type(4)));
typedef float  float2_t __attribute__((ext_vector_type(2)));
typedef __bf16 bf16x8   __attribute__((ext_vector_type(8)));

__device__ __forceinline__ float fexp2(float x){ return __builtin_amdgcn_exp2f(x); }
__device__ __forceinline__ float frcp (float x){ return __builtin_amdgcn_rcpf(x); }
__device__ __forceinline__ float sigm (float x){ return frcp(1.f + fexp2(-1.44269504f*x)); }
__device__ __forceinline__ float tanh_(float x){ return 1.f - 2.f*frcp(1.f + fexp2(2.88539008f*x)); }

// setup-only RNE split (weights; cost irrelevant)
__device__ __forceinline__ void split8(const float* v, bf16x8& hi, bf16x8& lo){
  #pragma unroll
  for (int j = 0; j < 8; j++){
    __bf16 h = (__bf16)v[j];
    hi[j] = h;
    lo[j] = (__bf16)(v[j] - (float)h);
  }
}

#define MFMA(a,b,c) __builtin_amdgcn_mfma_f32_16x16x32_bf16((a),(b),(c),0,0,0)

// ---- LDS layout ----
// ushort region: h exchange, double-buffered, rows stride 72 (16B-aligned)
#define HHI 0                 // 2 buf x [16 rows][72] hi
#define HLO 2304              // 2 buf x [16 rows][72] lo
#define HS_SZ 4608
// float region:
#define XOF 0                 // [16 rows][196] fp32 raw x staging
#define XPK 3136              // [64 t][16 rows][4] packed {x0,x1,x2,0}
#define OOF 7232              // [16 rows][196] fp32 out staging
#define GXO 10368             // gate exchange: [wg][srcHalf][tt][64 lanes][2]
#define LF_SZ 12416

__global__ __launch_bounds__(512, 2)
void LSTMAnomalyDetector_kernel(
    const float* __restrict__ x,     const float* __restrict__ W_ih,
    const float* __restrict__ W_hh,  const float* __restrict__ b_ih,
    const float* __restrict__ b_hh,  const float* __restrict__ W_dec,
    const float* __restrict__ b_dec, float* __restrict__ out)
{
  __shared__ __align__(16) unsigned short HS[HS_SZ];
  __shared__ __align__(16) float          LF[LF_SZ];

  const int tid  = threadIdx.x;
  const int w    = tid >> 6;        // wave 0..7
  const int wg   = w & 3;           // H-col block
  const int half = w >> 2;          // 0: gates i,f   1: gates g,o
  const int lane = tid & 63;
  const int q    = lane >> 4;       // quad 0..3
  const int lid  = lane & 15;
  const int b0   = blockIdx.x * ROWS;
  const int cw   = wg*16 + lid;     // this lane's H-column
  const int m0   = q*4 + half*2;    // my 2 batch rows: m0, m0+1

  // ---- resident weight fragments (B-operand: B[k=kt*32+q*8+j][n=lid]) ----
  bf16x8 Bh[2][2], Bl[2][2];  // W_hh^T hi/lo for my 2 gate tiles (tl=half*2+tt)
  bf16x8 Dh[2],    Dl[2];     // decoder: W_dec^T (cols 0..2 valid)
  float  wi[4][3], bsum[4];   // fp32 x-path: ALL 4 gates (needed at activation)

  #pragma unroll
  for (int tt = 0; tt < 2; tt++){
    const int g = (half*2 + tt)*64 + cw;        // gate row (W_hh[256][64])
    #pragma unroll
    for (int kt = 0; kt < 2; kt++){
      const float* p = W_hh + g*64 + kt*32 + q*8;
      float v[8];
      #pragma unroll
      for (int j = 0; j < 8; j++) v[j] = p[j];
      split8(v, Bh[tt][kt], Bl[tt][kt]);
    }
  }
  #pragma unroll
  for (int tl = 0; tl < 4; tl++){
    const int g = tl*64 + cw;
    wi[tl][0] = W_ih[g*3+0];
    wi[tl][1] = W_ih[g*3+1];
    wi[tl][2] = W_ih[g*3+2];
    bsum[tl]  = b_ih[g] + b_hh[g];
  }
  #pragma unroll
  for (int kt = 0; kt < 2; kt++){
    float v[8] = {0.f,0.f,0.f,0.f,0.f,0.f,0.f,0.f};
    if (lid < 3){
      const float* p = W_dec + lid*64 + kt*32 + q*8;
      #pragma unroll
      for (int j = 0; j < 8; j++) v[j] = p[j];
    }
    split8(v, Dh[kt], Dl[kt]);
  }
  const float bdec = (lid < 3) ? b_dec[lid] : 0.f;

  // ---- state ----
  bf16x8 ah0 = {}, ah1 = {}, al0 = {}, al1 = {};   // h_{t-1} A-frags (hi/lo)
  float creg[2] = {0.f, 0.f};                      // c for rows m0, m0+1 @ col cw
  float xp[4][2];                                  // fp32 x-part per gate, 2 rows

  auto loadx = [&](int d){
    float4_t xv0 = *(const float4_t*)&LF[XPK + d*64 + m0*4];
    float4_t xv1 = *(const float4_t*)&LF[XPK + d*64 + (m0+1)*4];
    #pragma unroll
    for (int tl = 0; tl < 4; tl++){
      xp[tl][0] = fmaf(wi[tl][2], xv0[2],
                    fmaf(wi[tl][1], xv0[1],
                      fmaf(wi[tl][0], xv0[0], bsum[tl])));
      xp[tl][1] = fmaf(wi[tl][2], xv1[2],
                    fmaf(wi[tl][1], xv1[1],
                      fmaf(wi[tl][0], xv1[0], bsum[tl])));
    }
  };

  // ---- preload + pack x chunk 0 (512 threads) ----
  #pragma unroll
  for (int s = 0; s < 2; s++){
    const int f = tid + 512*s;
    if (f < 768){
      const int row = f/48; const int off = (f%48)*4;
      float4_t v = *(const float4_t*)(x + (size_t)(b0+row)*1536 + off);
      *(float4_t*)&LF[XOF + row*196 + off] = v;
    }
  }
  __syncthreads();
  #pragma unroll
  for (int s = 0; s < 2; s++){
    const int p = tid + 512*s;                 // p = t*16 + row, 0..1023
    const float* xr = &LF[XOF + (p & 15)*196 + (p >> 4)*3];
    float4_t v = {xr[0], xr[1], xr[2], 0.f};
    *(float4_t*)&LF[XPK + p*4] = v;
  }
  __syncthreads();
  loadx(0);

  for (int t = 0; t < TLEN; ++t){
    const int dt = t & (TCHUNK-1);
    const int hb = (t & 1) * 1152;

    // my 2 gate tiles: full h-contribution (hi*Bh + lo*Bh + hi*Bl), as R4
    float4_t loc[2];
    #pragma unroll
    for (int tt = 0; tt < 2; tt++){
      float4_t accA = {0.f,0.f,0.f,0.f};
      accA = MFMA(ah0, Bh[tt][0], accA);
      accA = MFMA(ah1, Bh[tt][1], accA);
      accA = MFMA(al0, Bh[tt][0], accA);
      accA = MFMA(al1, Bh[tt][1], accA);
      float4_t accB = {0.f,0.f,0.f,0.f};
      accB = MFMA(ah0, Bl[tt][0], accB);
      accB = MFMA(ah1, Bl[tt][1], accB);
      loc[tt] = accA + accB;
    }

    // exchange write: send the 2 regs the partner half activates
    // (half=0 activates regs 0,1 so sends 2,3; half=1 symmetric)
    {
      float s00, s01, s10, s11;
      if (half == 0){ s00=loc[0][2]; s01=loc[0][3]; s10=loc[1][2]; s11=loc[1][3]; }
      else          { s00=loc[0][0]; s01=loc[0][1]; s10=loc[1][0]; s11=loc[1][1]; }
      float2_t v0 = {s00, s01}, v1 = {s10, s11};
      *(float2_t*)&LF[GXO + wg*512 + half*256 +   0 + lane*2] = v0;
      *(float2_t*)&LF[GXO + wg*512 + half*256 + 128 + lane*2] = v1;
    }
    __syncthreads();   // barrier A: exchange ready

    // read partner's 2 tiles; assemble my 2 cells' 4 gate preacts
    float2_t r0 = *(const float2_t*)&LF[GXO + wg*512 + (1-half)*256 +   0 + lane*2];
    float2_t r1 = *(const float2_t*)&LF[GXO + wg*512 + (1-half)*256 + 128 + lane*2];
    float vi0,vi1, vf0,vf1, vg0,vg1, vo0,vo1;
    if (half == 0){
      vi0=loc[0][0]; vi1=loc[0][1];       // my tiles are i,f; my regs 0,1
      vf0=loc[1][0]; vf1=loc[1][1];
      vg0=r0[0];     vg1=r0[1];           // partner's g,o for my rows
      vo0=r1[0];     vo1=r1[1];
    } else {
      vi0=r0[0];     vi1=r0[1];           // partner's i,f for my rows
      vf0=r1[0];     vf1=r1[1];
      vg0=loc[0][2]; vg1=loc[0][3];       // my tiles are g,o; my regs 2,3
      vo0=loc[1][2]; vo1=loc[1][3];
    }

    // lane-local activations for rows m0, m0+1; trunc h-split (R4's recipe)
    {
      const float ig = sigm (vi0 + xp[0][0]);
      const float fg = sigm (vf0 + xp[1][0]);
      const float gg = tanh_(vg0 + xp[2][0]);
      const float og = sigm (vo0 + xp[3][0]);
      creg[0] = fg*creg[0] + ig*gg;
      const float h = og * tanh_(creg[0]);
      const unsigned u  = __float_as_uint(h);
      const float    lf = h - __uint_as_float(u & 0xFFFF0000u);   // exact
      HS[HHI + hb + m0*72 + cw] = (unsigned short)(u >> 16);
      HS[HLO + hb + m0*72 + cw] = (unsigned short)(__float_as_uint(lf) >> 16);
    }
    {
      const float ig = sigm (vi1 + xp[0][1]);
      const float fg = sigm (vf1 + xp[1][1]);
      const float gg = tanh_(vg1 + xp[2][1]);
      const float og = sigm (vo1 + xp[3][1]);
      creg[1] = fg*creg[1] + ig*gg;
      const float h = og * tanh_(creg[1]);
      const unsigned u  = __float_as_uint(h);
      const float    lf = h - __uint_as_float(u & 0xFFFF0000u);
      HS[HHI + hb + (m0+1)*72 + cw] = (unsigned short)(u >> 16);
      HS[HLO + hb + (m0+1)*72 + cw] = (unsigned short)(__float_as_uint(lf) >> 16);
    }

    // prefetch next step's x-part (hides under barrier B)
    if (dt != TCHUNK-1) loadx(dt+1);

    __syncthreads();   // barrier B: h_t complete

    // rebuild A-frags: 4 raw ds_read_b128, zero VALU (R3/R4-verified pattern)
    {
      const unsigned short* ph = &HS[HHI + hb + lid*72 + q*8];
      const unsigned short* pl = &HS[HLO + hb + lid*72 + q*8];
      ah0 = *(const bf16x8*)&ph[0];
      ah1 = *(const bf16x8*)&ph[32];
      al0 = *(const bf16x8*)&pl[0];
      al1 = *(const bf16x8*)&pl[32];
    }

    // decoder rotates across 8 waves: out_t = h_t @ W_dec^T + b_dec -> OOF
    if (w == (t & 7)){
      float4_t d = {0.f,0.f,0.f,0.f};
      d = MFMA(ah0, Dh[0], d);
      d = MFMA(ah1, Dh[1], d);
      d = MFMA(al0, Dh[0], d);
      d = MFMA(al1, Dh[1], d);
      d = MFMA(ah0, Dl[0], d);
      d = MFMA(ah1, Dl[1], d);
      if (lid < 3){
        #pragma unroll
        for (int r = 0; r < 4; r++)
          LF[OOF + (q*4+r)*196 + dt*3 + lid] = d[r] + bdec;
      }
    }

    // chunk boundary: flush out, stage+pack next x chunk
    if (dt == TCHUNK-1){
      __syncthreads();
      const int t0 = t - (TCHUNK-1);
      #pragma unroll
      for (int s = 0; s < 2; s++){
        const int f = tid + 512*s;
        if (f < 768){
          const int row = f/48; const int off = (f%48)*4;
          float4_t v = *(const float4_t*)&LF[OOF + row*196 + off];
          *(float4_t*)(out + (size_t)(b0+row)*1536 + t0*3 + off) = v;
        }
      }
      if (t + 1 < TLEN){
        #pragma unroll
        for (int s = 0; s < 2; s++){
          const int f = tid + 512*s;
          if (f < 768){
            const int row = f/48; const int off = (f%48)*4;
            float4_t v = *(const float4_t*)(x + (size_t)(b0+row)*1536 + (t+1)*3 + off);
            *(float4_t*)&LF[XOF + row*196 + off] = v;
          }
        }
        __syncthreads();
        #pragma unroll
        for (int s = 0; s < 2; s++){
          const int p = tid + 512*s;
          const float* xr = &LF[XOF + (p & 15)*196 + (p >> 4)*3];
          float4_t v = {xr[0], xr[1], xr[2], 0.f};
          *(float4_t*)&LF[XPK + p*4] = v;
        }
      }
      __syncthreads();
      if (t + 1 < TLEN) loadx(0);
    }
  }
}

extern "C" void kernel_launch(void* const* d_in, const int* in_sizes, int n_in,
                              void* d_out, int out_size, void* d_ws, size_t ws_size,
                              hipStream_t stream)
{
  const float* x     = (const float*)d_in[0];
  const float* W_ih  = (const float*)d_in[1];
  const float* W_hh  = (const float*)d_in[2];
  const float* b_ih  = (const float*)d_in[3];
  const float* b_hh  = (const float*)d_in[4];
  const float* W_dec = (const float*)d_in[5];
  const float* b_dec = (const float*)d_in[6];
  float* out = (float*)d_out;

  const int B = in_sizes[0] / (TLEN * 3);   // 4096
  const int blocks = B / ROWS;              // 256
  hipLaunchKernelGGL(LSTMAnomalyDetector_kernel, dim3(blocks), dim3(512), 0, stream,
                     x, W_ih, W_hh, b_ih, b_hh, W_dec, b_dec, out);
}